// Round 1
// baseline (3392.199 us; speedup 1.0000x reference)
//
#include <hip/hip_runtime.h>
#include <hip/hip_bf16.h>

typedef unsigned short u16;
typedef unsigned char  u8;
typedef unsigned int   u32;

#define DEVI static __device__ __forceinline__

// ---- problem geometry ----
constexpr int B  = 2;
constexpr int C0 = 4,   D0 = 40, H0 = 256, W0 = 256;
constexpr int C1 = 32,  D1 = 20, H1 = 128, W1 = 128;
constexpr int C2 = 64;                       // same spatial as layer 1
constexpr int C3 = 128, D3 = 10, H3 = 64,  W3 = 64;
constexpr int S0 = D0 * H0 * W0;             // 2,621,440
constexpr int S1 = D1 * H1 * W1;             // 327,680
constexpr int S3 = D3 * H3 * W3;             // 40,960
constexpr int NV1 = B * S1;                  // 655,360
constexpr int NV3 = B * S3;                  // 81,920

// ---- bf16 helpers (bit-exact RNE, no NaN inputs here) ----
DEVI float b2f(u16 v) { return __uint_as_float(((u32)v) << 16); }
DEVI u16 f2b(float f) {
  u32 u = __float_as_uint(f);
  return (u16)((u + 0x7fffu + ((u >> 16) & 1u)) >> 16);
}
DEVI u32 pk2(float a, float b) { return (u32)f2b(a) | ((u32)f2b(b) << 16); }
DEVI void bf8_unpack(const uint4 u, float* f) {
  f[0] = b2f((u16)(u.x & 0xffffu)); f[1] = b2f((u16)(u.x >> 16));
  f[2] = b2f((u16)(u.y & 0xffffu)); f[3] = b2f((u16)(u.y >> 16));
  f[4] = b2f((u16)(u.z & 0xffffu)); f[5] = b2f((u16)(u.z >> 16));
  f[6] = b2f((u16)(u.w & 0xffffu)); f[7] = b2f((u16)(u.w >> 16));
}
DEVI void bf8_store(u16* dst, const float* f) {
  uint4 u;
  u.x = pk2(f[0], f[1]); u.y = pk2(f[2], f[3]);
  u.z = pk2(f[4], f[5]); u.w = pk2(f[6], f[7]);
  *reinterpret_cast<uint4*>(dst) = u;
}

// ---- weight repack: w[o][i][27] -> wL[t][i][o] (f32) ----
__global__ __launch_bounds__(256) void sl_repack(const float* __restrict__ src,
                                                 float* __restrict__ dst, int O, int I) {
  const int n = O * I * 27;
  const int i = blockIdx.x * 256 + threadIdx.x;
  if (i >= n) return;
  const int o = i % O;
  const int r = i / O;
  const int ci = r % I;
  const int t = r / I;
  dst[i] = src[(o * I + ci) * 27 + t];
}

// ---- conv1: features*(active==0) -> x1 raw (bf16 NDHWC32) + mask1 ----
__global__ __launch_bounds__(256) void sl_conv1(
    const float* __restrict__ feat, const int* __restrict__ act,
    const float* __restrict__ wL, u16* __restrict__ x1, u8* __restrict__ mask1) {
  const int idx = blockIdx.x * 256 + threadIdx.x;  // < NV1
  const int b = idx / S1;
  const int s = idx - b * S1;
  const int z = s >> 14, y = (s >> 7) & 127, x = s & 127;
  float acc[C1];
#pragma unroll
  for (int o = 0; o < C1; ++o) acc[o] = 0.f;
  bool any = false;
  for (int dz = 0; dz < 3; ++dz) {
    const int zi = 2 * z + dz - 1;
    if ((unsigned)zi >= (unsigned)D0) continue;
    for (int dy = 0; dy < 3; ++dy) {
      const int yi = 2 * y + dy - 1;
      if ((unsigned)yi >= (unsigned)H0) continue;
      for (int dx = 0; dx < 3; ++dx) {
        const int xi = 2 * x + dx - 1;
        if ((unsigned)xi >= (unsigned)W0) continue;
        const int sp = zi * (H0 * W0) + yi * W0 + xi;
        if (act[b * S0 + sp] == 0) {
          any = true;
          const size_t fb = (size_t)b * C0 * S0 + sp;
          const float f0 = feat[fb], f1 = feat[fb + S0],
                      f2 = feat[fb + 2 * (size_t)S0], f3 = feat[fb + 3 * (size_t)S0];
          const float* wt = wL + ((dz * 3 + dy) * 3 + dx) * (C0 * C1);
#pragma unroll
          for (int o = 0; o < C1; ++o)
            acc[o] = fmaf(f3, wt[3 * C1 + o],
                     fmaf(f2, wt[2 * C1 + o],
                     fmaf(f1, wt[C1 + o],
                     fmaf(f0, wt[o], acc[o]))));
        }
      }
    }
  }
  mask1[idx] = any ? (u8)1 : (u8)0;
  if (any) {
    u16* dst = x1 + (size_t)idx * C1;
#pragma unroll
    for (int g = 0; g < 4; ++g) bf8_store(dst + g * 8, acc + g * 8);
  }
}

// ---- conv2 (stride 1): BN1+ReLU+mask applied on load of x1 ----
__global__ __launch_bounds__(256) void sl_conv2(
    const u16* __restrict__ x1, const u8* __restrict__ mask1,
    const float* __restrict__ wL, const float* __restrict__ sc,
    const float* __restrict__ sh, u16* __restrict__ x2) {
  const int idx = blockIdx.x * 256 + threadIdx.x;  // < NV1
  if (!mask1[idx]) return;                          // output never consumed
  const int b = idx / S1;
  const int s = idx - b * S1;
  const int z = s >> 14, y = (s >> 7) & 127, x = s & 127;
  float acc[C2];
#pragma unroll
  for (int o = 0; o < C2; ++o) acc[o] = 0.f;
  for (int dz = 0; dz < 3; ++dz) {
    const int zi = z + dz - 1;
    if ((unsigned)zi >= (unsigned)D1) continue;
    for (int dy = 0; dy < 3; ++dy) {
      const int yi = y + dy - 1;
      if ((unsigned)yi >= (unsigned)H1) continue;
      for (int dx = 0; dx < 3; ++dx) {
        const int xi = x + dx - 1;
        if ((unsigned)xi >= (unsigned)W1) continue;
        const int v = (b * D1 + zi) * (H1 * W1) + yi * W1 + xi;
        if (!mask1[v]) continue;                    // y1 is 0 there
        const uint4* xp = reinterpret_cast<const uint4*>(x1 + (size_t)v * C1);
        const float* wt = wL + ((dz * 3 + dy) * 3 + dx) * (C1 * C2);
        float in[C1];
#pragma unroll
        for (int g = 0; g < 4; ++g) { uint4 u = xp[g]; bf8_unpack(u, in + g * 8); }
#pragma unroll
        for (int c = 0; c < C1; ++c) in[c] = fmaxf(fmaf(in[c], sc[c], sh[c]), 0.f);
#pragma unroll 4
        for (int c = 0; c < C1; ++c) {
          const float ic = in[c];
          const float* wr = wt + c * C2;
#pragma unroll
          for (int o = 0; o < C2; ++o) acc[o] = fmaf(ic, wr[o], acc[o]);
        }
      }
    }
  }
  u16* dst = x2 + (size_t)idx * C2;
#pragma unroll
  for (int g = 0; g < 8; ++g) bf8_store(dst + g * 8, acc + g * 8);
}

// ---- conv3 (stride 2): BN2+ReLU+mask on load; also emits mask3 ----
__global__ __launch_bounds__(256) void sl_conv3(
    const u16* __restrict__ x2, const u8* __restrict__ mask1,
    const float* __restrict__ wL, const float* __restrict__ sc,
    const float* __restrict__ sh, u16* __restrict__ x3, u8* __restrict__ mask3) {
  const int gid = blockIdx.x * 256 + threadIdx.x;  // < NV3
  const int oh = blockIdx.y;                       // output-channel half (0/1)
  const int b = gid / S3;
  const int s = gid - b * S3;
  const int z = s >> 12, y = (s >> 6) & 63, x = s & 63;
  float acc[64];
#pragma unroll
  for (int o = 0; o < 64; ++o) acc[o] = 0.f;
  bool any = false;
  for (int dz = 0; dz < 3; ++dz) {
    const int zi = 2 * z + dz - 1;
    if ((unsigned)zi >= (unsigned)D1) continue;
    for (int dy = 0; dy < 3; ++dy) {
      const int yi = 2 * y + dy - 1;
      if ((unsigned)yi >= (unsigned)H1) continue;
      for (int dx = 0; dx < 3; ++dx) {
        const int xi = 2 * x + dx - 1;
        if ((unsigned)xi >= (unsigned)W1) continue;
        const int v = (b * D1 + zi) * (H1 * W1) + yi * W1 + xi;
        if (!mask1[v]) continue;
        any = true;
        const uint4* xp = reinterpret_cast<const uint4*>(x2 + (size_t)v * C2);
        const float* wt = wL + ((dz * 3 + dy) * 3 + dx) * (C2 * C3) + oh * 64;
#pragma unroll 1
        for (int cc = 0; cc < 8; ++cc) {
          float f[8];
          uint4 u = xp[cc];
          bf8_unpack(u, f);
#pragma unroll
          for (int j = 0; j < 8; ++j) {
            const int c = cc * 8 + j;
            const float ic = fmaxf(fmaf(f[j], sc[c], sh[c]), 0.f);
            const float* wr = wt + c * C3;
#pragma unroll
            for (int o = 0; o < 64; ++o) acc[o] = fmaf(ic, wr[o], acc[o]);
          }
        }
      }
    }
  }
  if (oh == 0) mask3[gid] = any ? (u8)1 : (u8)0;
  if (any) {
    u16* dst = x3 + (size_t)gid * C3 + oh * 64;
#pragma unroll
    for (int g = 0; g < 8; ++g) bf8_store(dst + g * 8, acc + g * 8);
  }
}

// ---- masked per-channel sum / sumsq (32-channel groups via blockIdx.y) ----
__global__ __launch_bounds__(256) void sl_stats(
    const u16* __restrict__ x, const u8* __restrict__ mask, int C, int nvox,
    float* __restrict__ sum, float* __restrict__ ssq, float* __restrict__ cnt) {
  const int co = blockIdx.y * 32;
  float s[32], q[32];
#pragma unroll
  for (int j = 0; j < 32; ++j) { s[j] = 0.f; q[j] = 0.f; }
  float c0 = 0.f;
  for (int v = blockIdx.x * blockDim.x + threadIdx.x; v < nvox;
       v += gridDim.x * blockDim.x) {
    if (!mask[v]) continue;
    c0 += 1.f;
    const uint4* xp = reinterpret_cast<const uint4*>(x + (size_t)v * C + co);
#pragma unroll
    for (int g = 0; g < 4; ++g) {
      float f[8];
      bf8_unpack(xp[g], f);
#pragma unroll
      for (int j = 0; j < 8; ++j) {
        const float vv = f[j];
        s[g * 8 + j] += vv;
        q[g * 8 + j] += vv * vv;
      }
    }
  }
  for (int m = 1; m < 64; m <<= 1) {
#pragma unroll
    for (int j = 0; j < 32; ++j) {
      s[j] += __shfl_xor(s[j], m);
      q[j] += __shfl_xor(q[j], m);
    }
    c0 += __shfl_xor(c0, m);
  }
  if ((threadIdx.x & 63) == 0) {
#pragma unroll
    for (int j = 0; j < 32; ++j) {
      atomicAdd(&sum[co + j], s[j]);
      atomicAdd(&ssq[co + j], q[j]);
    }
    if (cnt != nullptr && blockIdx.y == 0) atomicAdd(cnt, c0);
  }
}

// ---- finalize BN: scale/shift per channel ----
__global__ void sl_finalize(const float* __restrict__ sum, const float* __restrict__ ssq,
                            const float* __restrict__ cnt, const float* __restrict__ gamma,
                            const float* __restrict__ beta, float* __restrict__ sc,
                            float* __restrict__ sh, int C) {
  const int c = threadIdx.x;
  if (c >= C) return;
  const float n = *cnt;
  const float m = sum[c] / n;
  const float var = fmaxf(ssq[c] / n - m * m, 0.f);
  const float s = gamma[c] * rsqrtf(var + 1e-5f);
  sc[c] = s;
  sh[c] = beta[c] - m * s;
}

// ---- heads: BN3+ReLU+mask then 3-wide & 7-wide dot per voxel ----
__global__ __launch_bounds__(256) void sl_heads(
    const u16* __restrict__ x3, const u8* __restrict__ mask3,
    const float* __restrict__ sc, const float* __restrict__ sh,
    const float* __restrict__ Wc, const float* __restrict__ bc,
    const float* __restrict__ Wr, const float* __restrict__ br,
    float* __restrict__ out) {
  const int gid = blockIdx.x * 256 + threadIdx.x;  // < NV3
  const int b = gid / S3;
  const int s = gid - b * S3;
  float aC[3] = {0.f, 0.f, 0.f};
  float aR[7] = {0.f, 0.f, 0.f, 0.f, 0.f, 0.f, 0.f};
  if (mask3[gid]) {
#pragma unroll
    for (int k = 0; k < 3; ++k) aC[k] = bc[k];
#pragma unroll
    for (int k = 0; k < 7; ++k) aR[k] = br[k];
    const uint4* xp = reinterpret_cast<const uint4*>(x3 + (size_t)gid * C3);
#pragma unroll 2
    for (int g = 0; g < 16; ++g) {
      float f[8];
      bf8_unpack(xp[g], f);
#pragma unroll
      for (int j = 0; j < 8; ++j) {
        const int c = g * 8 + j;
        const float y = fmaxf(fmaf(f[j], sc[c], sh[c]), 0.f);
#pragma unroll
        for (int k = 0; k < 3; ++k) aC[k] = fmaf(y, Wc[k * C3 + c], aC[k]);
#pragma unroll
        for (int k = 0; k < 7; ++k) aR[k] = fmaf(y, Wr[k * C3 + c], aR[k]);
      }
    }
  }
#pragma unroll
  for (int k = 0; k < 3; ++k) out[(size_t)(b * 3 + k) * S3 + s] = aC[k];
  const size_t ob = (size_t)B * 3 * S3;
#pragma unroll
  for (int k = 0; k < 7; ++k) out[ob + (size_t)(b * 7 + k) * S3 + s] = aR[k];
}

extern "C" void kernel_launch(void* const* d_in, const int* in_sizes, int n_in,
                              void* d_out, int out_size, void* d_ws, size_t ws_size,
                              hipStream_t stream) {
  (void)in_sizes; (void)n_in; (void)out_size; (void)ws_size;
  const float* feat = (const float*)d_in[0];
  const int*   act  = (const int*)d_in[1];
  const float* w1 = (const float*)d_in[2];
  const float* g1 = (const float*)d_in[3];
  const float* b1 = (const float*)d_in[4];
  const float* w2 = (const float*)d_in[5];
  const float* g2 = (const float*)d_in[6];
  const float* b2 = (const float*)d_in[7];
  const float* w3 = (const float*)d_in[8];
  const float* g3 = (const float*)d_in[9];
  const float* b3 = (const float*)d_in[10];
  const float* Wc = (const float*)d_in[11];
  const float* bc = (const float*)d_in[12];
  const float* Wr = (const float*)d_in[13];
  const float* br = (const float*)d_in[14];
  float* out = (float*)d_out;

  char* ws = (char*)d_ws;
  size_t off = 0;
  auto take = [&](size_t bytes) {
    char* p = ws + off;
    off = (off + bytes + 255) & ~(size_t)255;
    return p;
  };
  u16* x1 = (u16*)take((size_t)NV1 * C1 * 2);   //  42 MB
  u16* x2 = (u16*)take((size_t)NV1 * C2 * 2);   //  84 MB
  u16* x3 = (u16*)take((size_t)NV3 * C3 * 2);   //  21 MB
  u8* mask1 = (u8*)take(NV1);
  u8* mask3 = (u8*)take(NV3);
  float* w1L = (float*)take((size_t)27 * C0 * C1 * 4);
  float* w2L = (float*)take((size_t)27 * C1 * C2 * 4);
  float* w3L = (float*)take((size_t)27 * C2 * C3 * 4);
  float* stats  = (float*)take(450 * 4);
  float* scales = (float*)take(448 * 4);

  float* sum1 = stats,       *ssq1 = stats + 32;
  float* sum2 = stats + 64,  *ssq2 = stats + 128;
  float* sum3 = stats + 192, *ssq3 = stats + 320;
  float* cnt1 = stats + 448, *cnt3 = stats + 449;
  float* sc1 = scales,       *sh1 = scales + 32;
  float* sc2 = scales + 64,  *sh2 = scales + 128;
  float* sc3 = scales + 192, *sh3 = scales + 320;

  hipMemsetAsync(stats, 0, 450 * 4, stream);
  sl_repack<<<(27 * C0 * C1 + 255) / 256, 256, 0, stream>>>(w1, w1L, C1, C0);
  sl_repack<<<(27 * C1 * C2 + 255) / 256, 256, 0, stream>>>(w2, w2L, C2, C1);
  sl_repack<<<(27 * C2 * C3 + 255) / 256, 256, 0, stream>>>(w3, w3L, C3, C2);

  sl_conv1<<<NV1 / 256, 256, 0, stream>>>(feat, act, w1L, x1, mask1);
  sl_stats<<<dim3(128, 1), 256, 0, stream>>>(x1, mask1, C1, NV1, sum1, ssq1, cnt1);
  sl_finalize<<<1, 32, 0, stream>>>(sum1, ssq1, cnt1, g1, b1, sc1, sh1, 32);

  sl_conv2<<<NV1 / 256, 256, 0, stream>>>(x1, mask1, w2L, sc1, sh1, x2);
  sl_stats<<<dim3(128, 2), 256, 0, stream>>>(x2, mask1, C2, NV1, sum2, ssq2, nullptr);
  sl_finalize<<<1, 64, 0, stream>>>(sum2, ssq2, cnt1, g2, b2, sc2, sh2, 64);

  sl_conv3<<<dim3(NV3 / 256, 2), 256, 0, stream>>>(x2, mask1, w3L, sc2, sh2, x3, mask3);
  sl_stats<<<dim3(32, 4), 256, 0, stream>>>(x3, mask3, C3, NV3, sum3, ssq3, cnt3);
  sl_finalize<<<1, 128, 0, stream>>>(sum3, ssq3, cnt3, g3, b3, sc3, sh3, 128);

  sl_heads<<<NV3 / 256, 256, 0, stream>>>(x3, mask3, sc3, sh3, Wc, bc, Wr, br, out);
}

// Round 2
// 1243.373 us; speedup vs baseline: 2.7282x; 2.7282x over previous
//
#include <hip/hip_runtime.h>
#include <hip/hip_bf16.h>

typedef unsigned short u16;
typedef unsigned char  u8;
typedef unsigned int   u32;

typedef short bf16x8 __attribute__((ext_vector_type(8)));
typedef float f32x4  __attribute__((ext_vector_type(4)));

#define DEVI static __device__ __forceinline__

// ---- problem geometry ----
constexpr int B  = 2;
constexpr int C0 = 4,   D0 = 40, H0 = 256, W0 = 256;
constexpr int C1 = 32,  D1 = 20, H1 = 128, W1 = 128;
constexpr int C2 = 64;                       // same spatial as layer 1
constexpr int C3 = 128, D3 = 10, H3 = 64,  W3 = 64;
constexpr int S0 = D0 * H0 * W0;
constexpr int S1 = D1 * H1 * W1;             // 327,680
constexpr int S3 = D3 * H3 * W3;             // 40,960
constexpr int NV1 = B * S1;                  // 655,360
constexpr int NV3 = B * S3;                  // 81,920

// ---- bf16 helpers ----
DEVI float b2f(u16 v) { return __uint_as_float(((u32)v) << 16); }
DEVI u16 f2b(float f) {
  u32 u = __float_as_uint(f);
  return (u16)((u + 0x7fffu + ((u >> 16) & 1u)) >> 16);
}
DEVI u32 pk2(float a, float b) { return (u32)f2b(a) | ((u32)f2b(b) << 16); }
DEVI void bf8_unpack(const uint4 u, float* f) {
  f[0] = b2f((u16)(u.x & 0xffffu)); f[1] = b2f((u16)(u.x >> 16));
  f[2] = b2f((u16)(u.y & 0xffffu)); f[3] = b2f((u16)(u.y >> 16));
  f[4] = b2f((u16)(u.z & 0xffffu)); f[5] = b2f((u16)(u.z >> 16));
  f[6] = b2f((u16)(u.w & 0xffffu)); f[7] = b2f((u16)(u.w >> 16));
}
DEVI void bf8_store(u16* dst, const float* f) {
  uint4 u;
  u.x = pk2(f[0], f[1]); u.y = pk2(f[2], f[3]);
  u.z = pk2(f[4], f[5]); u.w = pk2(f[6], f[7]);
  *reinterpret_cast<uint4*>(dst) = u;
}

// ---- weight repack for conv1: w[o][i][27] -> wL[t][i][o] (f32) ----
__global__ __launch_bounds__(256) void sl_repack(const float* __restrict__ src,
                                                 float* __restrict__ dst, int O, int I) {
  const int n = O * I * 27;
  const int i = blockIdx.x * 256 + threadIdx.x;
  if (i >= n) return;
  const int o = i % O;
  const int r = i / O;
  const int ci = r % I;
  const int t = r / I;
  dst[i] = src[(o * I + ci) * 27 + t];
}

// ---- weight repack to MFMA A-fragment order (bf16) ----
// dst[((t*kkN + kk)*mbN + mb)*64 + lane][j] = w[o = mb*16 + (lane&15)][i = kk*32 + (lane>>4)*8 + j][t]
__global__ __launch_bounds__(256) void sl_repackA(const float* __restrict__ src,
                                                  u16* __restrict__ dst, int I, int O) {
  const int mbN = O / 16, kkN = I / 32;
  const int total = 27 * kkN * mbN * 64;
  const int idx = blockIdx.x * 256 + threadIdx.x;
  if (idx >= total) return;
  const int l = idx & 63;
  int r = idx >> 6;
  const int mb = r % mbN; r /= mbN;
  const int kk = r % kkN;
  const int t = r / kkN;
  const int o = mb * 16 + (l & 15);
  const int i0 = kk * 32 + (l >> 4) * 8;
  float f[8];
#pragma unroll
  for (int j = 0; j < 8; ++j) f[j] = src[((size_t)o * I + i0 + j) * 27 + t];
  bf8_store(dst + (size_t)idx * 8, f);
}

// ---- conv1: features*(active==0) -> x1 raw (bf16 NDHWC32) + mask1 ----
__global__ __launch_bounds__(256) void sl_conv1(
    const float* __restrict__ feat, const int* __restrict__ act,
    const float* __restrict__ wL, u16* __restrict__ x1, u8* __restrict__ mask1) {
  const int idx = blockIdx.x * 256 + threadIdx.x;
  const int b = idx / S1;
  const int s = idx - b * S1;
  const int z = s >> 14, y = (s >> 7) & 127, x = s & 127;
  float acc[C1];
#pragma unroll
  for (int o = 0; o < C1; ++o) acc[o] = 0.f;
  bool any = false;
  for (int dz = 0; dz < 3; ++dz) {
    const int zi = 2 * z + dz - 1;
    if ((unsigned)zi >= (unsigned)D0) continue;
    for (int dy = 0; dy < 3; ++dy) {
      const int yi = 2 * y + dy - 1;
      if ((unsigned)yi >= (unsigned)H0) continue;
      for (int dx = 0; dx < 3; ++dx) {
        const int xi = 2 * x + dx - 1;
        if ((unsigned)xi >= (unsigned)W0) continue;
        const int sp = zi * (H0 * W0) + yi * W0 + xi;
        if (act[b * S0 + sp] == 0) {
          any = true;
          const size_t fb = (size_t)b * C0 * S0 + sp;
          const float f0 = feat[fb], f1 = feat[fb + S0],
                      f2 = feat[fb + 2 * (size_t)S0], f3 = feat[fb + 3 * (size_t)S0];
          const float* wt = wL + ((dz * 3 + dy) * 3 + dx) * (C0 * C1);
#pragma unroll
          for (int o = 0; o < C1; ++o)
            acc[o] = fmaf(f3, wt[3 * C1 + o],
                     fmaf(f2, wt[2 * C1 + o],
                     fmaf(f1, wt[C1 + o],
                     fmaf(f0, wt[o], acc[o]))));
        }
      }
    }
  }
  mask1[idx] = any ? (u8)1 : (u8)0;
  if (any) {
    u16* dst = x1 + (size_t)idx * C1;
#pragma unroll
    for (int g = 0; g < 4; ++g) bf8_store(dst + g * 8, acc + g * 8);
  }
}

// ---- mask3 = dilation of mask1, stride 2 ----
__global__ __launch_bounds__(256) void sl_mask3(const u8* __restrict__ mask1,
                                                u8* __restrict__ mask3) {
  const int gid = blockIdx.x * 256 + threadIdx.x;
  if (gid >= NV3) return;
  const int b = gid / S3;
  const int s = gid - b * S3;
  const int z = s >> 12, y = (s >> 6) & 63, x = s & 63;
  bool any = false;
  for (int dz = 0; dz < 3; ++dz) {
    const int zi = 2 * z + dz - 1;
    if ((unsigned)zi >= (unsigned)D1) continue;
    for (int dy = 0; dy < 3; ++dy) {
      const int yi = 2 * y + dy - 1;
      if ((unsigned)yi >= (unsigned)H1) continue;
      for (int dx = 0; dx < 3; ++dx) {
        const int xi = 2 * x + dx - 1;
        if ((unsigned)xi >= (unsigned)W1) continue;
        if (mask1[((b * D1 + zi) * H1 + yi) * W1 + xi]) any = true;
      }
    }
  }
  mask3[gid] = any ? (u8)1 : (u8)0;
}

// ---- in-place BN+ReLU+mask: x <- mask ? relu(x*sc+sh) : 0 ----
template <int C>
__global__ __launch_bounds__(256) void sl_bnrelu(
    u16* __restrict__ x, const u8* __restrict__ mask,
    const float* __restrict__ sc, const float* __restrict__ sh, int nvox) {
  const int v = blockIdx.x * 256 + threadIdx.x;
  if (v >= nvox) return;
  u16* p = x + (size_t)v * C;
  if (mask[v]) {
#pragma unroll
    for (int g = 0; g < C / 8; ++g) {
      float f[8];
      bf8_unpack(reinterpret_cast<const uint4*>(p)[g], f);
#pragma unroll
      for (int j = 0; j < 8; ++j)
        f[j] = fmaxf(fmaf(f[j], sc[g * 8 + j], sh[g * 8 + j]), 0.f);
      bf8_store(p + g * 8, f);
    }
  } else {
    const uint4 zz = {0u, 0u, 0u, 0u};
#pragma unroll
    for (int g = 0; g < C / 8; ++g) reinterpret_cast<uint4*>(p)[g] = zz;
  }
}

// ---- conv2 (stride 1) implicit GEMM via MFMA: y1[NV1,32] -> x2[NV1,64] ----
// block = 256 (4 waves), wave w owns out-channels [w*16, w*16+16), tile = 64 voxels along x
__global__ __launch_bounds__(256) void sl_conv2_mfma(
    const u16* __restrict__ y1, const u16* __restrict__ wA, u16* __restrict__ x2) {
  const int wid  = threadIdx.x >> 6;
  const int lane = threadIdx.x & 63;
  const int col  = lane & 15;
  const int kg   = lane >> 4;
  bf16x8 a[27];
#pragma unroll
  for (int t = 0; t < 27; ++t)
    a[t] = *reinterpret_cast<const bf16x8*>(wA + ((size_t)(t * 4 + wid) * 64 + lane) * 8);
  const int ntiles = NV1 / 64;  // 10240
  for (int tile = blockIdx.x; tile < ntiles; tile += gridDim.x) {
    const int xh = (tile & 1) * 64;      // W1/64 = 2 tiles per row
    const int rowid = tile >> 1;         // (b*D1 + z)*H1 + y
    const int y = rowid & (H1 - 1);
    const int bz = rowid >> 7;           // b*D1 + z
    const int z = bz % D1;
    f32x4 acc[4];
#pragma unroll
    for (int nb = 0; nb < 4; ++nb) acc[nb] = f32x4{0.f, 0.f, 0.f, 0.f};
#pragma unroll
    for (int t = 0; t < 27; ++t) {
      const int dz = t / 9, dy = (t / 3) % 3, dx = t % 3;
      const int zi = z + dz - 1;
      const int yi = y + dy - 1;
      if ((unsigned)zi >= (unsigned)D1 || (unsigned)yi >= (unsigned)H1) continue;
      const int base = ((bz + dz - 1) * H1 + yi) * W1;
      const int x0 = xh + col + dx - 1;
#pragma unroll
      for (int nb = 0; nb < 4; ++nb) {
        const int xi = x0 + nb * 16;
        bf16x8 bfr = {0, 0, 0, 0, 0, 0, 0, 0};
        if ((unsigned)xi < (unsigned)W1)
          bfr = *reinterpret_cast<const bf16x8*>(y1 + (size_t)(base + xi) * 32 + kg * 8);
        acc[nb] = __builtin_amdgcn_mfma_f32_16x16x32_bf16(a[t], bfr, acc[nb], 0, 0, 0);
      }
    }
    u16* dst = x2 + ((size_t)tile * 64 + col) * 64 + wid * 16 + kg * 4;
#pragma unroll
    for (int nb = 0; nb < 4; ++nb) {
      uint2 pp;
      pp.x = pk2(acc[nb][0], acc[nb][1]);
      pp.y = pk2(acc[nb][2], acc[nb][3]);
      *reinterpret_cast<uint2*>(dst + (size_t)nb * 16 * 64) = pp;
    }
  }
}

// ---- conv3 (stride 2) implicit GEMM via MFMA: y2[NV1,64] -> x3[NV3,128] ----
// block = 512 (8 waves), wave w owns out-channels [w*16, ...), tile = one output row (64 voxels)
__global__ __launch_bounds__(512) void sl_conv3_mfma(
    const u16* __restrict__ y2, const u16* __restrict__ wA, u16* __restrict__ x3) {
  const int wid  = threadIdx.x >> 6;   // 0..7
  const int lane = threadIdx.x & 63;
  const int col  = lane & 15;
  const int kg   = lane >> 4;
  const int tile = blockIdx.x;         // 1280 rows
  const int y = tile & (W3 - 1);
  const int r = tile >> 6;
  const int z = r % D3;
  const int b = r / D3;
  f32x4 acc[4];
#pragma unroll
  for (int nb = 0; nb < 4; ++nb) acc[nb] = f32x4{0.f, 0.f, 0.f, 0.f};
#pragma unroll
  for (int t = 0; t < 27; ++t) {
    const int dz = t / 9, dy = (t / 3) % 3, dx = t % 3;
    const int zi = 2 * z + dz - 1;
    const int yi = 2 * y + dy - 1;
    if ((unsigned)zi >= (unsigned)D1 || (unsigned)yi >= (unsigned)H1) continue;
    const int base = ((b * D1 + zi) * H1 + yi) * W1;
    const int x0 = 2 * col + dx - 1;
#pragma unroll
    for (int kk = 0; kk < 2; ++kk) {
      const bf16x8 a =
          *reinterpret_cast<const bf16x8*>(wA + ((size_t)((t * 2 + kk) * 8 + wid) * 64 + lane) * 8);
#pragma unroll
      for (int nb = 0; nb < 4; ++nb) {
        const int xi = x0 + nb * 32;
        bf16x8 bfr = {0, 0, 0, 0, 0, 0, 0, 0};
        if ((unsigned)xi < (unsigned)W1)
          bfr = *reinterpret_cast<const bf16x8*>(y2 + (size_t)(base + xi) * 64 + kk * 32 + kg * 8);
        acc[nb] = __builtin_amdgcn_mfma_f32_16x16x32_bf16(a, bfr, acc[nb], 0, 0, 0);
      }
    }
  }
  u16* dst = x3 + ((size_t)tile * 64 + col) * 128 + wid * 16 + kg * 4;
#pragma unroll
  for (int nb = 0; nb < 4; ++nb) {
    uint2 pp;
    pp.x = pk2(acc[nb][0], acc[nb][1]);
    pp.y = pk2(acc[nb][2], acc[nb][3]);
    *reinterpret_cast<uint2*>(dst + (size_t)nb * 16 * 128) = pp;
  }
}

// ---- masked per-channel sum / sumsq (32-channel groups via blockIdx.y) ----
__global__ __launch_bounds__(256) void sl_stats(
    const u16* __restrict__ x, const u8* __restrict__ mask, int C, int nvox,
    float* __restrict__ sum, float* __restrict__ ssq, float* __restrict__ cnt) {
  const int co = blockIdx.y * 32;
  float s[32], q[32];
#pragma unroll
  for (int j = 0; j < 32; ++j) { s[j] = 0.f; q[j] = 0.f; }
  float c0 = 0.f;
  for (int v = blockIdx.x * blockDim.x + threadIdx.x; v < nvox;
       v += gridDim.x * blockDim.x) {
    if (!mask[v]) continue;
    c0 += 1.f;
    const uint4* xp = reinterpret_cast<const uint4*>(x + (size_t)v * C + co);
#pragma unroll
    for (int g = 0; g < 4; ++g) {
      float f[8];
      bf8_unpack(xp[g], f);
#pragma unroll
      for (int j = 0; j < 8; ++j) {
        const float vv = f[j];
        s[g * 8 + j] += vv;
        q[g * 8 + j] += vv * vv;
      }
    }
  }
  for (int m = 1; m < 64; m <<= 1) {
#pragma unroll
    for (int j = 0; j < 32; ++j) {
      s[j] += __shfl_xor(s[j], m);
      q[j] += __shfl_xor(q[j], m);
    }
    c0 += __shfl_xor(c0, m);
  }
  if ((threadIdx.x & 63) == 0) {
#pragma unroll
    for (int j = 0; j < 32; ++j) {
      atomicAdd(&sum[co + j], s[j]);
      atomicAdd(&ssq[co + j], q[j]);
    }
    if (cnt != nullptr && blockIdx.y == 0) atomicAdd(cnt, c0);
  }
}

// ---- finalize BN: scale/shift per channel ----
__global__ void sl_finalize(const float* __restrict__ sum, const float* __restrict__ ssq,
                            const float* __restrict__ cnt, const float* __restrict__ gamma,
                            const float* __restrict__ beta, float* __restrict__ sc,
                            float* __restrict__ sh, int C) {
  const int c = threadIdx.x;
  if (c >= C) return;
  const float n = *cnt;
  const float m = sum[c] / n;
  const float var = fmaxf(ssq[c] / n - m * m, 0.f);
  const float s = gamma[c] * rsqrtf(var + 1e-5f);
  sc[c] = s;
  sh[c] = beta[c] - m * s;
}

// ---- heads: BN3+ReLU+mask then 3-wide & 7-wide dot per voxel ----
__global__ __launch_bounds__(256) void sl_heads(
    const u16* __restrict__ x3, const u8* __restrict__ mask3,
    const float* __restrict__ sc, const float* __restrict__ sh,
    const float* __restrict__ Wc, const float* __restrict__ bc,
    const float* __restrict__ Wr, const float* __restrict__ br,
    float* __restrict__ out) {
  const int gid = blockIdx.x * 256 + threadIdx.x;
  const int b = gid / S3;
  const int s = gid - b * S3;
  float aC[3] = {0.f, 0.f, 0.f};
  float aR[7] = {0.f, 0.f, 0.f, 0.f, 0.f, 0.f, 0.f};
  if (mask3[gid]) {
#pragma unroll
    for (int k = 0; k < 3; ++k) aC[k] = bc[k];
#pragma unroll
    for (int k = 0; k < 7; ++k) aR[k] = br[k];
    const uint4* xp = reinterpret_cast<const uint4*>(x3 + (size_t)gid * C3);
#pragma unroll 2
    for (int g = 0; g < 16; ++g) {
      float f[8];
      bf8_unpack(xp[g], f);
#pragma unroll
      for (int j = 0; j < 8; ++j) {
        const int c = g * 8 + j;
        const float y = fmaxf(fmaf(f[j], sc[c], sh[c]), 0.f);
#pragma unroll
        for (int k = 0; k < 3; ++k) aC[k] = fmaf(y, Wc[k * C3 + c], aC[k]);
#pragma unroll
        for (int k = 0; k < 7; ++k) aR[k] = fmaf(y, Wr[k * C3 + c], aR[k]);
      }
    }
  }
#pragma unroll
  for (int k = 0; k < 3; ++k) out[(size_t)(b * 3 + k) * S3 + s] = aC[k];
  const size_t ob = (size_t)B * 3 * S3;
#pragma unroll
  for (int k = 0; k < 7; ++k) out[ob + (size_t)(b * 7 + k) * S3 + s] = aR[k];
}

extern "C" void kernel_launch(void* const* d_in, const int* in_sizes, int n_in,
                              void* d_out, int out_size, void* d_ws, size_t ws_size,
                              hipStream_t stream) {
  (void)in_sizes; (void)n_in; (void)out_size; (void)ws_size;
  const float* feat = (const float*)d_in[0];
  const int*   act  = (const int*)d_in[1];
  const float* w1 = (const float*)d_in[2];
  const float* g1 = (const float*)d_in[3];
  const float* b1 = (const float*)d_in[4];
  const float* w2 = (const float*)d_in[5];
  const float* g2 = (const float*)d_in[6];
  const float* b2 = (const float*)d_in[7];
  const float* w3 = (const float*)d_in[8];
  const float* g3 = (const float*)d_in[9];
  const float* b3 = (const float*)d_in[10];
  const float* Wc = (const float*)d_in[11];
  const float* bc = (const float*)d_in[12];
  const float* Wr = (const float*)d_in[13];
  const float* br = (const float*)d_in[14];
  float* out = (float*)d_out;

  char* ws = (char*)d_ws;
  size_t off = 0;
  auto take = [&](size_t bytes) {
    char* p = ws + off;
    off = (off + bytes + 255) & ~(size_t)255;
    return p;
  };
  u16* x1 = (u16*)take((size_t)NV1 * C1 * 2);   //  42 MB (raw conv1, then y1 in-place)
  u16* x2 = (u16*)take((size_t)NV1 * C2 * 2);   //  84 MB (raw conv2, then y2 in-place)
  u16* x3 = (u16*)take((size_t)NV3 * C3 * 2);   //  21 MB
  u8* mask1 = (u8*)take(NV1);
  u8* mask3 = (u8*)take(NV3);
  float* w1L = (float*)take((size_t)27 * C0 * C1 * 4);
  u16* wA2 = (u16*)take((size_t)27 * 1 * 4 * 64 * 8 * 2);   // 110 KB
  u16* wA3 = (u16*)take((size_t)27 * 2 * 8 * 64 * 8 * 2);   // 442 KB
  float* stats  = (float*)take(450 * 4);
  float* scales = (float*)take(448 * 4);

  float* sum1 = stats,       *ssq1 = stats + 32;
  float* sum2 = stats + 64,  *ssq2 = stats + 128;
  float* sum3 = stats + 192, *ssq3 = stats + 320;
  float* cnt1 = stats + 448, *cnt3 = stats + 449;
  float* sc1 = scales,       *sh1 = scales + 32;
  float* sc2 = scales + 64,  *sh2 = scales + 128;
  float* sc3 = scales + 192, *sh3 = scales + 320;

  hipMemsetAsync(stats, 0, 450 * 4, stream);
  sl_repack<<<(27 * C0 * C1 + 255) / 256, 256, 0, stream>>>(w1, w1L, C1, C0);
  sl_repackA<<<(27 * 1 * 4 * 64 + 255) / 256, 256, 0, stream>>>(w2, wA2, 32, 64);
  sl_repackA<<<(27 * 2 * 8 * 64 + 255) / 256, 256, 0, stream>>>(w3, wA3, 64, 128);

  sl_conv1<<<NV1 / 256, 256, 0, stream>>>(feat, act, w1L, x1, mask1);
  sl_mask3<<<(NV3 + 255) / 256, 256, 0, stream>>>(mask1, mask3);
  sl_stats<<<dim3(128, 1), 256, 0, stream>>>(x1, mask1, C1, NV1, sum1, ssq1, cnt1);
  sl_finalize<<<1, 32, 0, stream>>>(sum1, ssq1, cnt1, g1, b1, sc1, sh1, 32);
  sl_bnrelu<32><<<(NV1 + 255) / 256, 256, 0, stream>>>(x1, mask1, sc1, sh1, NV1);

  sl_conv2_mfma<<<2560, 256, 0, stream>>>(x1, wA2, x2);
  sl_stats<<<dim3(128, 2), 256, 0, stream>>>(x2, mask1, C2, NV1, sum2, ssq2, nullptr);
  sl_finalize<<<1, 64, 0, stream>>>(sum2, ssq2, cnt1, g2, b2, sc2, sh2, 64);
  sl_bnrelu<64><<<(NV1 + 255) / 256, 256, 0, stream>>>(x2, mask1, sc2, sh2, NV1);

  sl_conv3_mfma<<<1280, 512, 0, stream>>>(x2, wA3, x3);
  sl_stats<<<dim3(32, 4), 256, 0, stream>>>(x3, mask3, C3, NV3, sum3, ssq3, cnt3);
  sl_finalize<<<1, 128, 0, stream>>>(sum3, ssq3, cnt3, g3, b3, sc3, sh3, 128);

  sl_heads<<<NV3 / 256, 256, 0, stream>>>(x3, mask3, sc3, sh3, Wc, bc, Wr, br, out);
}